// Round 23
// baseline (119.005 us; speedup 1.0000x reference)
//
#include <hip/hip_runtime.h>

#define BN 8192      // B*N
#define NP 1024      // N
#define NF 64        // F_OUT
#define NSEG 8192
#define NBIN 1024    // bins of 8 segments (bin = seg >> 3)
#define CAPBIN 1184  // Poisson(1024) + 5 sigma; 8*148; overflow exact
#define WREC 148     // records per wave slice
#define OVF_MAX 4096
#define OVFS (1 << 30)

typedef float f32x4 __attribute__((ext_vector_type(4)));

// K1: blocks [0,nsb): block-local counting sort into dense per-bin strips.
//     blocks [nsb,..): x1-MLP with W1/W2 staged in LDS (16 rows amortize).
__global__ __launch_bounds__(1024) void prep_kernel(
    const float* __restrict__ x,
    const float* __restrict__ W1, const float* __restrict__ b1,
    const float* __restrict__ W2, const float* __restrict__ b2,
    const int* __restrict__ eb, const int* __restrict__ ei,
    const int* __restrict__ ej, const int* __restrict__ ek,
    int* __restrict__ gcur, int2* __restrict__ rec,
    int* __restrict__ ovf_cnt, int4* __restrict__ ovf,
    float* __restrict__ x1,
    int nnz, int nsb)
{
    __shared__ int smem[8192];                 // 32 KB, dual-purpose
    if ((int)blockIdx.x < nsb) {
        int* hist = smem;                      // [0,1024)
        int* cur  = smem + 1024;               // [1024,2048)
        const int t = threadIdx.x;
        hist[t] = 0;
        __syncthreads();

        int segs[8], jks[8];
        const int base = blockIdx.x * 8192;
        #pragma unroll
        for (int q = 0; q < 2; ++q) {
            const int e0 = base + (q * 1024 + t) * 4;
            if (e0 < nnz) {
                const int4 b4 = *(const int4*)(eb + e0);
                const int4 i4 = *(const int4*)(ei + e0);
                const int4 j4 = *(const int4*)(ej + e0);
                const int4 k4 = *(const int4*)(ek + e0);
                segs[q*4+0] = b4.x * NP + i4.x;  jks[q*4+0] = (j4.x << 10) | k4.x;
                segs[q*4+1] = b4.y * NP + i4.y;  jks[q*4+1] = (j4.y << 10) | k4.y;
                segs[q*4+2] = b4.z * NP + i4.z;  jks[q*4+2] = (j4.z << 10) | k4.z;
                segs[q*4+3] = b4.w * NP + i4.w;  jks[q*4+3] = (j4.w << 10) | k4.w;
                #pragma unroll
                for (int c = 0; c < 4; ++c)
                    atomicAdd(&hist[segs[q*4+c] >> 3], 1);
            } else {
                #pragma unroll
                for (int c = 0; c < 4; ++c) segs[q*4+c] = -1;
            }
        }
        __syncthreads();

        {
            const int v = hist[t];
            int c = 0;
            if (v > 0) {
                const int r = atomicAdd(&gcur[t], v);
                if (r + v <= CAPBIN) {
                    c = t * CAPBIN + r;
                } else {
                    atomicSub(&gcur[t], v);
                    c = OVFS + atomicAdd(ovf_cnt, v);
                }
            }
            cur[t] = c;
        }
        __syncthreads();

        #pragma unroll
        for (int q = 0; q < 2; ++q) {
            #pragma unroll
            for (int c = 0; c < 4; ++c) {
                const int idx = q * 4 + c;
                if (segs[idx] >= 0) {
                    const int e = base + (q * 1024 + t) * 4 + c;
                    const int seg = segs[idx];
                    const int p = atomicAdd(&cur[seg >> 3], 1);   // LDS atomic
                    if (p < OVFS) {
                        rec[p] = make_int2(e | ((seg & 7) << 20), jks[idx]);
                    } else {
                        const int o = p - OVFS;
                        if (o < OVF_MAX) ovf[o] = make_int4(seg, e, jks[idx], 0);
                    }
                }
            }
        }
    } else {
        float* w1l = (float*)smem;             // 16 KB
        float* w2l = (float*)(smem + 4096);    // 16 KB
        const int t = threadIdx.x;
        ((float4*)w1l)[t] = ((const float4*)W1)[t];   // 1024 float4 each
        ((float4*)w2l)[t] = ((const float4*)W2)[t];
        __syncthreads();

        const int row = ((int)blockIdx.x - nsb) * 16 + (t >> 6);
        const int lane = t & 63;
        const float xv = x[(size_t)row * NF + lane];
        float a1 = b1[lane];
        #pragma unroll 8
        for (int c = 0; c < NF; ++c)
            a1 = fmaf(__shfl(xv, c), w1l[c * NF + lane], a1);
        const float h1 = fmaxf(a1, 0.f);
        float o1 = b2[lane];
        #pragma unroll 8
        for (int c = 0; c < NF; ++c)
            o1 = fmaf(__shfl(h1, c), w2l[c * NF + lane], o1);
        x1[(size_t)row * NF + lane] = fmaxf(o1, 0.f);
    }
}

// K2: block per bin (512 thr = 8 waves). Ballot-aggregated seg-split (no LDS
// atomics, strip read ONCE into registers), then the proven per-seg gather
// loop + fused self-MLP epilogue (pure store).
__global__ __launch_bounds__(512, 8) void gather_kernel(
    const f32x4* __restrict__ Wv4, const f32x4* __restrict__ x14,
    const float* __restrict__ x,
    const float* __restrict__ Ws1, const float* __restrict__ bs1,
    const float* __restrict__ Ws2, const float* __restrict__ bs2,
    const int* __restrict__ gcur, const int2* __restrict__ rec,
    const int* __restrict__ ovf_cnt, const int4* __restrict__ ovf,
    f32x4* __restrict__ out4)
{
    __shared__ int2 srt[CAPBIN];
    __shared__ float smlp[8][NF];
    __shared__ int wcnt[8][8];           // [wave][seg]
    __shared__ int tots[8], base2s[8], woff[8][8];
    const int bin = blockIdx.x;
    const int t = threadIdx.x;
    const int w    = t >> 6;
    const int lane = t & 63;
    const int cnt = gcur[bin];

    // self-MLP for seg = bin*8 + w (same-wave smlp use: no barrier needed)
    {
        const int seg = bin * 8 + w;
        const float xv = x[(size_t)seg * NF + lane];
        float a2 = bs1[lane];
        #pragma unroll 8
        for (int c = 0; c < NF; ++c)
            a2 = fmaf(__shfl(xv, c), Ws1[c * NF + lane], a2);
        const float h2 = fmaxf(a2, 0.f);
        float o2 = bs2[lane];
        #pragma unroll 8
        for (int c = 0; c < NF; ++c)
            o2 = fmaf(__shfl(h2, c), Ws2[c * NF + lane], o2);
        smlp[w][lane] = fmaxf(o2, 0.f);
    }

    // load this wave's strip slice into registers (single global pass)
    const int lo = w * WREC;
    const int nrec = cnt - lo;                 // valid if index < nrec
    const int2* strip = rec + (size_t)bin * CAPBIN;
    const int2 r0 = strip[lo + lane];          // loads stay inside ws: masked below
    const int2 r1 = strip[lo + 64 + lane];
    const int2 r2 = strip[lo + 128 + lane];
    const bool v0 = lane < nrec && lane < WREC;
    const bool v1 = 64 + lane < nrec && 64 + lane < WREC;
    const bool v2 = 128 + lane < nrec && 128 + lane < WREC;
    const int s0 = (r0.x >> 20) & 7, s1 = (r1.x >> 20) & 7, s2 = (r2.x >> 20) & 7;

    // per-wave per-seg counts via ballot (no LDS atomics)
    #pragma unroll
    for (int s = 0; s < 8; ++s) {
        const int c = __popcll(__ballot(v0 && s0 == s))
                    + __popcll(__ballot(v1 && s1 == s))
                    + __popcll(__ballot(v2 && s2 == s));
        if (lane == 0) wcnt[w][s] = c;
    }
    __syncthreads();                            // wcnt visible

    if (t < 8) {                                // wave 0: totals, bases, offsets
        int tot = 0;
        #pragma unroll
        for (int ww = 0; ww < 8; ++ww) tot += wcnt[ww][t];
        tots[t] = tot;
        int b2 = 0;
        for (int s = 0; s < t; ++s) b2 += tots[s];   // same-wave LDS, ordered
        base2s[t] = b2;
        int run = b2;
        #pragma unroll
        for (int ww = 0; ww < 8; ++ww) { woff[ww][t] = run; run += wcnt[ww][t]; }
    }
    __syncthreads();                            // woff visible

    // scatter from registers with ballot-prefix positions
    {
        int wof[8];
        #pragma unroll
        for (int s = 0; s < 8; ++s) wof[s] = woff[w][s];
        const unsigned long long lt = (1ULL << lane) - 1ULL;
        #pragma unroll
        for (int s = 0; s < 8; ++s) {
            unsigned long long mb = __ballot(v0 && s0 == s);
            if (v0 && s0 == s) srt[wof[s] + __popcll(mb & lt)] = r0;
            wof[s] += __popcll(mb);
        }
        #pragma unroll
        for (int s = 0; s < 8; ++s) {
            unsigned long long mb = __ballot(v1 && s1 == s);
            if (v1 && s1 == s) srt[wof[s] + __popcll(mb & lt)] = r1;
            wof[s] += __popcll(mb);
        }
        #pragma unroll
        for (int s = 0; s < 8; ++s) {
            unsigned long long mb = __ballot(v2 && s2 == s);
            if (v2 && s2 == s) srt[wof[s] + __popcll(mb & lt)] = r2;
            wof[s] += __popcll(mb);
        }
    }
    __syncthreads();                            // srt ready

    const int sub  = lane >> 4;
    const int c16  = lane & 15;
    const int seg  = bin * 8 + w;
    const int b    = seg >> 10;
    const f32x4* __restrict__ x1b = x14 + ((size_t)b << 10) * 16;
    const int cs = tots[w], bs = base2s[w];
    int dtrue = cs;

    f32x4 acc = {0.f, 0.f, 0.f, 0.f};
    #pragma unroll 2
    for (int it = 0; it < cs; it += 4) {
        int idx = it + sub;
        const float m = (idx < cs) ? 1.f : 0.f;
        idx = min(idx, cs - 1);                 // cs >= 1 inside loop
        const int2 r = srt[bs + idx];
        const int e = r.x & 0xFFFFF;
        const int j = (r.y >> 10) & 1023, k = r.y & 1023;
        const f32x4 wv = __builtin_nontemporal_load(Wv4 + (size_t)e * 16 + c16);
        const f32x4 xj = x1b[j * 16 + c16];
        const f32x4 xk = x1b[k * 16 + c16];
        acc += (m * wv) * (xj * xk);
    }

    // exact overflow path (expected empty)
    const int novf = min(ovf_cnt[0], OVF_MAX);
    if (novf > 0) {
        for (int o = 0; o < novf; ++o) {
            const int4 r = ovf[o];
            if (r.x == seg) {
                ++dtrue;
                const float m = (sub == 0) ? 1.f : 0.f;
                const int j = (r.z >> 10) & 1023, k = r.z & 1023;
                const f32x4 wv = Wv4[(size_t)(unsigned)r.y * 16 + c16];
                acc += (m * wv) * (x1b[j * 16 + c16] * x1b[k * 16 + c16]);
            }
        }
    }

    #pragma unroll
    for (int mm = 16; mm < 64; mm <<= 1) {
        acc.x += __shfl_xor(acc.x, mm);
        acc.y += __shfl_xor(acc.y, mm);
        acc.z += __shfl_xor(acc.z, mm);
        acc.w += __shfl_xor(acc.w, mm);
    }

    if (sub == 0) {
        const float a = 1.0f / ((float)dtrue + 1e-10f);
        const f32x4 mv = *(const f32x4*)&smlp[w][c16 * 4];
        out4[(size_t)seg * 16 + c16] = mv + a * acc;   // pure store
    }
}

extern "C" void kernel_launch(void* const* d_in, const int* in_sizes, int n_in,
                              void* d_out, int out_size, void* d_ws, size_t ws_size,
                              hipStream_t stream) {
    const float* x   = (const float*)d_in[0];
    const float* Wv  = (const float*)d_in[1];
    const int*   eb  = (const int*)d_in[2];
    const int*   ei  = (const int*)d_in[3];
    const int*   ej  = (const int*)d_in[4];
    const int*   ek  = (const int*)d_in[5];
    const float* W1  = (const float*)d_in[6];
    const float* b1  = (const float*)d_in[7];
    const float* W2  = (const float*)d_in[8];
    const float* b2  = (const float*)d_in[9];
    const float* Ws1 = (const float*)d_in[10];
    const float* bs1 = (const float*)d_in[11];
    const float* Ws2 = (const float*)d_in[12];
    const float* bs2 = (const float*)d_in[13];
    float* out = (float*)d_out;
    const int nnz = in_sizes[2];

    char* ws = (char*)d_ws;
    float* x1    = (float*)ws;                             // [0, 2MB)
    int* gcur    = (int*)(ws + (2 << 20));                 // NBIN ints
    int* ovf_cnt = gcur + NBIN;                            // 4 B
    int4* ovf    = (int4*)(ws + (2 << 20) + (64 << 10));   // 64 KB
    int2* rec    = (int2*)(ws + (4 << 20));                // 9.7 MB (+ slack after)

    const int nsb = (nnz + 8191) / 8192;   // 128 sort blocks (1024 thr x 8 edges)
    const int nmlp = BN / 16;              // 512 MLP blocks (16 waves x 1 row)

    (void)hipMemsetAsync(gcur, 0, (NBIN + 1) * sizeof(int), stream);
    prep_kernel<<<nsb + nmlp, 1024, 0, stream>>>(x, W1, b1, W2, b2,
                                                 eb, ei, ej, ek, gcur, rec, ovf_cnt, ovf,
                                                 x1, nnz, nsb);
    gather_kernel<<<NBIN, 512, 0, stream>>>((const f32x4*)Wv, (const f32x4*)x1,
                                            x, Ws1, bs1, Ws2, bs2,
                                            gcur, rec, ovf_cnt, ovf, (f32x4*)out);
}

// Round 24
// 113.018 us; speedup vs baseline: 1.0530x; 1.0530x over previous
//
#include <hip/hip_runtime.h>

#define BN 8192      // B*N
#define NP 1024      // N
#define NF 64        // F_OUT
#define NSEG 8192
#define NBIN 1024    // bins of 8 segments (bin = seg >> 3)
#define CAPBIN 1184  // Poisson(1024) + 5 sigma; overflow exact
#define OVF_MAX 4096
#define OVFS (1 << 30)   // sentinel: cursor values >= OVFS index the ovf list

typedef float f32x4 __attribute__((ext_vector_type(4)));

// K1: blocks [0,nsb): block-local counting sort of 8192 edges into dense global
//     per-bin strips. blocks [nsb,..): x1-MLP only, 16 rows/block.
__global__ __launch_bounds__(1024) void prep_kernel(
    const float* __restrict__ x,
    const float* __restrict__ W1, const float* __restrict__ b1,
    const float* __restrict__ W2, const float* __restrict__ b2,
    const int* __restrict__ eb, const int* __restrict__ ei,
    const int* __restrict__ ej, const int* __restrict__ ek,
    int* __restrict__ gcur, int2* __restrict__ rec,
    int* __restrict__ ovf_cnt, int4* __restrict__ ovf,
    float* __restrict__ x1,
    int nnz, int nsb)
{
    if ((int)blockIdx.x < nsb) {
        __shared__ int hist[NBIN];
        __shared__ int cur[NBIN];
        const int t = threadIdx.x;
        hist[t] = 0;
        __syncthreads();

        int segs[8], jks[8];
        const int base = blockIdx.x * 8192;
        #pragma unroll
        for (int q = 0; q < 2; ++q) {
            const int e0 = base + (q * 1024 + t) * 4;
            if (e0 < nnz) {
                const int4 b4 = *(const int4*)(eb + e0);
                const int4 i4 = *(const int4*)(ei + e0);
                const int4 j4 = *(const int4*)(ej + e0);
                const int4 k4 = *(const int4*)(ek + e0);
                segs[q*4+0] = b4.x * NP + i4.x;  jks[q*4+0] = (j4.x << 10) | k4.x;
                segs[q*4+1] = b4.y * NP + i4.y;  jks[q*4+1] = (j4.y << 10) | k4.y;
                segs[q*4+2] = b4.z * NP + i4.z;  jks[q*4+2] = (j4.z << 10) | k4.z;
                segs[q*4+3] = b4.w * NP + i4.w;  jks[q*4+3] = (j4.w << 10) | k4.w;
                #pragma unroll
                for (int c = 0; c < 4; ++c)
                    atomicAdd(&hist[segs[q*4+c] >> 3], 1);
            } else {
                #pragma unroll
                for (int c = 0; c < 4; ++c) segs[q*4+c] = -1;
            }
        }
        __syncthreads();

        {
            const int v = hist[t];
            int c = 0;
            if (v > 0) {
                const int r = atomicAdd(&gcur[t], v);
                if (r + v <= CAPBIN) {
                    c = t * CAPBIN + r;
                } else {
                    atomicSub(&gcur[t], v);
                    c = OVFS + atomicAdd(ovf_cnt, v);
                }
            }
            cur[t] = c;
        }
        __syncthreads();

        #pragma unroll
        for (int q = 0; q < 2; ++q) {
            #pragma unroll
            for (int c = 0; c < 4; ++c) {
                const int idx = q * 4 + c;
                if (segs[idx] >= 0) {
                    const int e = base + (q * 1024 + t) * 4 + c;
                    const int seg = segs[idx];
                    const int p = atomicAdd(&cur[seg >> 3], 1);   // LDS atomic
                    if (p < OVFS) {
                        rec[p] = make_int2(e | ((seg & 7) << 20), jks[idx]);
                    } else {
                        const int o = p - OVFS;
                        if (o < OVF_MAX) ovf[o] = make_int4(seg, e, jks[idx], 0);
                    }
                }
            }
        }
    } else {
        // x1-MLP only (self-MLP lives in gather): one wave per row
        const int row = ((int)blockIdx.x - nsb) * 16 + ((int)threadIdx.x >> 6);
        const int t = threadIdx.x & 63;
        const float xv = x[(size_t)row * NF + t];
        float a1 = b1[t];
        #pragma unroll 8
        for (int c = 0; c < NF; ++c)
            a1 = fmaf(__shfl(xv, c), W1[c * NF + t], a1);
        const float h1 = fmaxf(a1, 0.f);
        float o1 = b2[t];
        #pragma unroll 8
        for (int c = 0; c < NF; ++c)
            o1 = fmaf(__shfl(h1, c), W2[c * NF + t], o1);
        x1[(size_t)row * NF + t] = fmaxf(o1, 0.f);
    }
}

// K2: block per bin (512 thr = 8 waves). R17 gather + self-MLP epilogue:
// wave w computes the self-MLP for its seg (shfl bcast, weights L2-hot), and
// the final write is a pure store (no out read).
__global__ __launch_bounds__(512, 8) void gather_kernel(
    const f32x4* __restrict__ Wv4, const f32x4* __restrict__ x14,
    const float* __restrict__ x,
    const float* __restrict__ Ws1, const float* __restrict__ bs1,
    const float* __restrict__ Ws2, const float* __restrict__ bs2,
    const int* __restrict__ gcur, const int2* __restrict__ rec,
    const int* __restrict__ ovf_cnt, const int4* __restrict__ ovf,
    f32x4* __restrict__ out4)
{
    __shared__ int2 srt[CAPBIN];
    __shared__ float smlp[8][NF];
    __shared__ int hist[8], cur2[8], base2[8];
    const int bin = blockIdx.x;
    const int t = threadIdx.x;
    const int w    = t >> 6;
    const int lane = t & 63;
    const int cnt = gcur[bin];
    if (t < 8) hist[t] = 0;

    // self-MLP for seg = bin*8 + w (independent of the sort; issues early)
    {
        const int seg = bin * 8 + w;
        const float xv = x[(size_t)seg * NF + lane];
        float a2 = bs1[lane];
        #pragma unroll 8
        for (int c = 0; c < NF; ++c)
            a2 = fmaf(__shfl(xv, c), Ws1[c * NF + lane], a2);
        const float h2 = fmaxf(a2, 0.f);
        float o2 = bs2[lane];
        #pragma unroll 8
        for (int c = 0; c < NF; ++c)
            o2 = fmaf(__shfl(h2, c), Ws2[c * NF + lane], o2);
        smlp[w][lane] = fmaxf(o2, 0.f);
    }
    __syncthreads();

    const int2* strip = rec + (size_t)bin * CAPBIN;
    #pragma unroll
    for (int i = 0; i < 3; ++i) {                  // 3*512 >= CAPBIN
        const int idx = i * 512 + t;
        if (idx < cnt) atomicAdd(&hist[(strip[idx].x >> 20) & 7], 1);
    }
    __syncthreads();
    if (t < 8) {
        int bsum = 0;
        for (int s = 0; s < t; ++s) bsum += hist[s];
        base2[t] = bsum; cur2[t] = bsum;
    }
    __syncthreads();
    #pragma unroll
    for (int i = 0; i < 3; ++i) {                  // L2-hot second pass
        const int idx = i * 512 + t;
        if (idx < cnt) {
            const int2 r = strip[idx];
            srt[atomicAdd(&cur2[(r.x >> 20) & 7], 1)] = r;
        }
    }
    __syncthreads();

    const int sub  = lane >> 4;
    const int c16  = lane & 15;
    const int seg  = bin * 8 + w;
    const int b    = seg >> 10;
    const f32x4* __restrict__ x1b = x14 + ((size_t)b << 10) * 16;
    const int cs = hist[w], bs = base2[w];
    int dtrue = cs;

    f32x4 acc = {0.f, 0.f, 0.f, 0.f};
    #pragma unroll 2
    for (int it = 0; it < cs; it += 4) {
        int idx = it + sub;
        const float m = (idx < cs) ? 1.f : 0.f;
        idx = min(idx, cs - 1);                     // cs >= 1 inside loop
        const int2 r = srt[bs + idx];
        const int e = r.x & 0xFFFFF;
        const int j = (r.y >> 10) & 1023, k = r.y & 1023;
        const f32x4 wv = __builtin_nontemporal_load(Wv4 + (size_t)e * 16 + c16);
        const f32x4 xj = x1b[j * 16 + c16];
        const f32x4 xk = x1b[k * 16 + c16];
        acc += (m * wv) * (xj * xk);
    }

    // exact overflow path (expected empty)
    const int novf = min(ovf_cnt[0], OVF_MAX);
    if (novf > 0) {
        for (int o = 0; o < novf; ++o) {
            const int4 r = ovf[o];
            if (r.x == seg) {
                ++dtrue;
                const float m = (sub == 0) ? 1.f : 0.f;
                const int j = (r.z >> 10) & 1023, k = r.z & 1023;
                const f32x4 wv = Wv4[(size_t)(unsigned)r.y * 16 + c16];
                acc += (m * wv) * (x1b[j * 16 + c16] * x1b[k * 16 + c16]);
            }
        }
    }

    #pragma unroll
    for (int mm = 16; mm < 64; mm <<= 1) {
        acc.x += __shfl_xor(acc.x, mm);
        acc.y += __shfl_xor(acc.y, mm);
        acc.z += __shfl_xor(acc.z, mm);
        acc.w += __shfl_xor(acc.w, mm);
    }

    if (sub == 0) {
        const float a = 1.0f / ((float)dtrue + 1e-10f);
        const f32x4 mv = *(const f32x4*)&smlp[w][c16 * 4];
        out4[(size_t)seg * 16 + c16] = mv + a * acc;   // pure store, no RMW
    }
}

extern "C" void kernel_launch(void* const* d_in, const int* in_sizes, int n_in,
                              void* d_out, int out_size, void* d_ws, size_t ws_size,
                              hipStream_t stream) {
    const float* x   = (const float*)d_in[0];
    const float* Wv  = (const float*)d_in[1];
    const int*   eb  = (const int*)d_in[2];
    const int*   ei  = (const int*)d_in[3];
    const int*   ej  = (const int*)d_in[4];
    const int*   ek  = (const int*)d_in[5];
    const float* W1  = (const float*)d_in[6];
    const float* b1  = (const float*)d_in[7];
    const float* W2  = (const float*)d_in[8];
    const float* b2  = (const float*)d_in[9];
    const float* Ws1 = (const float*)d_in[10];
    const float* bs1 = (const float*)d_in[11];
    const float* Ws2 = (const float*)d_in[12];
    const float* bs2 = (const float*)d_in[13];
    float* out = (float*)d_out;
    const int nnz = in_sizes[2];

    char* ws = (char*)d_ws;
    float* x1    = (float*)ws;                             // [0, 2MB)
    int* gcur    = (int*)(ws + (2 << 20));                 // NBIN ints
    int* ovf_cnt = gcur + NBIN;                            // 4 B
    int4* ovf    = (int4*)(ws + (2 << 20) + (64 << 10));   // 64 KB
    int2* rec    = (int2*)(ws + (4 << 20));                // 9.7 MB

    const int nsb = (nnz + 8191) / 8192;   // 128 sort blocks (1024 thr x 8 edges)
    const int nmlp = BN / 16;              // 512 MLP blocks (16 waves x 1 row)

    (void)hipMemsetAsync(gcur, 0, (NBIN + 1) * sizeof(int), stream);
    prep_kernel<<<nsb + nmlp, 1024, 0, stream>>>(x, W1, b1, W2, b2,
                                                 eb, ei, ej, ek, gcur, rec, ovf_cnt, ovf,
                                                 x1, nnz, nsb);
    gather_kernel<<<NBIN, 512, 0, stream>>>((const f32x4*)Wv, (const f32x4*)x1,
                                            x, Ws1, bs1, Ws2, bs2,
                                            gcur, rec, ovf_cnt, ovf, (f32x4*)out);
}